// Round 1
// baseline (756.897 us; speedup 1.0000x reference)
//
#include <hip/hip_runtime.h>
#include <stdint.h>

// Problem constants (fixed by the reference setup)
constexpr int NROWS = 1000000;
constexpr int D = 64;
constexpr int B = 64;
constexpr int TOPK = 5;

#define WS_QK_OFF   64           // bytes: qk[64*64] floats
#define WS_PART_OFF 16448        // bytes: partial top-5 keys, u64 per candidate
#define MAX_NB      1024

// ---- monotonic float<->uint key (total order, works for negatives) ----
__device__ __forceinline__ unsigned fkey(float x) {
    unsigned u = __float_as_uint(x);
    return (u & 0x80000000u) ? ~u : (u | 0x80000000u);
}
__device__ __forceinline__ float fkey_inv(unsigned k) {
    unsigned u = (k & 0x80000000u) ? (k ^ 0x80000000u) : ~k;
    return __uint_as_float(u);
}

__global__ void k_init(unsigned* mm) {
    mm[0] = 0xFFFFFFFFu;  // identity for atomicMin of keys
    mm[1] = 0u;           // identity for atomicMax of keys
}

__global__ void k_minmax(const float4* __restrict__ mem4, int n4, unsigned* mm) {
    int t = threadIdx.x;
    int gid = blockIdx.x * blockDim.x + t;
    int stride = gridDim.x * blockDim.x;
    float mn = 3.402823466e38f, mx = -3.402823466e38f;
    for (int i = gid; i < n4; i += stride) {
        float4 v = mem4[i];
        mn = fminf(mn, fminf(fminf(v.x, v.y), fminf(v.z, v.w)));
        mx = fmaxf(mx, fmaxf(fmaxf(v.x, v.y), fmaxf(v.z, v.w)));
    }
    __shared__ float smn[256], smx[256];
    smn[t] = mn; smx[t] = mx;
    __syncthreads();
    for (int s = 128; s > 0; s >>= 1) {
        if (t < s) {
            smn[t] = fminf(smn[t], smn[t + s]);
            smx[t] = fmaxf(smx[t], smx[t + s]);
        }
        __syncthreads();
    }
    if (t == 0) {
        atomicMin(&mm[0], fkey(smn[0]));
        atomicMax(&mm[1], fkey(smx[0]));
    }
}

// qk = (query @ Wq^T) @ Wk, prescaled by 1/sqrt(D)=0.125
__global__ void k_qk(const float* __restrict__ query, const float* __restrict__ Wq,
                     const float* __restrict__ Wk, float* __restrict__ qk) {
    __shared__ float q[B * D];
    int t = threadIdx.x;
    for (int i = t; i < B * D; i += 256) {
        int b = i >> 6, d = i & 63;
        float s = 0.f;
        for (int e = 0; e < D; e++) s += query[b * D + e] * Wq[d * D + e];
        q[i] = s;
    }
    __syncthreads();
    for (int i = t; i < B * D; i += 256) {
        int b = i >> 6, e = i & 63;
        float s = 0.f;
        for (int d = 0; d < D; d++) s += q[b * D + d] * Wk[d * D + e];
        qk[i] = s * 0.125f;
    }
}

// Main pass: dequantize rows, score vs all 64 batches (lane==batch), keep
// per-lane top-5, merge per-block, emit packed u64 (score_key<<32)|~idx.
__launch_bounds__(256, 4)
__global__ void k_scores(const float* __restrict__ mem, const float* __restrict__ aw,
                         const float* __restrict__ qk, const unsigned* __restrict__ mm,
                         unsigned long long* __restrict__ part, int rowsPerBlock) {
    __shared__ float tile[64 * 64];
    __shared__ float awt[64];
    __shared__ unsigned long long cand[4 * 64 * TOPK];

    int t = threadIdx.x;
    int lane = t & 63;
    int wave = t >> 6;

    float mnv = fkey_inv(mm[0]);
    float mxv = fkey_inv(mm[1]);
    float scale = (mxv - mnv) / 255.0f;
    float zp = -mnv / scale;

    float qr[64];
    #pragma unroll
    for (int d = 0; d < 64; d++) qr[d] = qk[lane * 64 + d];

    float bs[TOPK]; int bi[TOPK];
    #pragma unroll
    for (int j = 0; j < TOPK; j++) { bs[j] = -3.402823466e38f; bi[j] = 0; }

    int row0 = blockIdx.x * rowsPerBlock;
    int rowEnd = min(row0 + rowsPerBlock, NROWS);

    for (int base = row0; base < rowEnd; base += 64) {
        __syncthreads();
        // stage+dequantize 64 rows into LDS (coalesced float4)
        #pragma unroll
        for (int i = 0; i < 4; i++) {
            int flat = (i * 256 + t) * 4;
            int g = base * 64 + flat;
            float4 v = make_float4(0.f, 0.f, 0.f, 0.f);
            if (g < NROWS * 64) v = *(const float4*)(mem + g);
            v.x = (rintf(v.x / scale + zp) - zp) * scale;
            v.y = (rintf(v.y / scale + zp) - zp) * scale;
            v.z = (rintf(v.z / scale + zp) - zp) * scale;
            v.w = (rintf(v.w / scale + zp) - zp) * scale;
            *(float4*)(tile + flat) = v;
        }
        if (t < 64) awt[t] = (base + t < NROWS) ? aw[base + t] : 0.f;
        __syncthreads();

        int lim = min(64, rowEnd - base);
        for (int r = wave; r < lim; r += 4) {
            const float4* rv = (const float4*)(tile + r * 64);
            float a0 = 0.f, a1 = 0.f, a2 = 0.f, a3 = 0.f;
            #pragma unroll
            for (int i = 0; i < 16; i++) {
                float4 v = rv[i];
                a0 += v.x * qr[4 * i + 0];
                a1 += v.y * qr[4 * i + 1];
                a2 += v.z * qr[4 * i + 2];
                a3 += v.w * qr[4 * i + 3];
            }
            float sc = (a0 + a1) + (a2 + a3) + awt[r];
            int gr = base + r;
            if (sc > bs[4]) {
                int p = 4;
                if (sc > bs[3]) { bs[4] = bs[3]; bi[4] = bi[3]; p = 3;
                  if (sc > bs[2]) { bs[3] = bs[2]; bi[3] = bi[2]; p = 2;
                    if (sc > bs[1]) { bs[2] = bs[1]; bi[2] = bi[1]; p = 1;
                      if (sc > bs[0]) { bs[1] = bs[0]; bi[1] = bi[0]; p = 0; } } } }
                bs[p] = sc; bi[p] = gr;
            }
        }
    }

    __syncthreads();
    #pragma unroll
    for (int j = 0; j < TOPK; j++) {
        cand[(wave * 64 + lane) * TOPK + j] =
            ((unsigned long long)fkey(bs[j]) << 32) | (unsigned)(~(unsigned)bi[j]);
    }
    __syncthreads();
    if (t < 64) {
        unsigned long long ts[TOPK];
        #pragma unroll
        for (int j = 0; j < TOPK; j++) ts[j] = 0ull;
        for (int w = 0; w < 4; w++) {
            #pragma unroll
            for (int j = 0; j < TOPK; j++) {
                unsigned long long k = cand[(w * 64 + t) * TOPK + j];
                if (k > ts[4]) {
                    int p = 4;
                    if (k > ts[3]) { ts[4] = ts[3]; p = 3;
                      if (k > ts[2]) { ts[3] = ts[2]; p = 2;
                        if (k > ts[1]) { ts[2] = ts[1]; p = 1;
                          if (k > ts[0]) { ts[1] = ts[0]; p = 0; } } } }
                    ts[p] = k;
                }
            }
        }
        #pragma unroll
        for (int j = 0; j < TOPK; j++)
            part[((long long)blockIdx.x * 64 + t) * TOPK + j] = ts[j];
    }
}

// One block per batch: merge nb*5 candidates -> top-5, softmax, weighted sum
// of dequantized mem rows, then @ Wv^T.
__global__ void k_finalize(const unsigned long long* __restrict__ part, int nb,
                           const float* __restrict__ mem, const float* __restrict__ Wv,
                           const unsigned* __restrict__ mm, float* __restrict__ out) {
    __shared__ unsigned long long keys[MAX_NB * TOPK];
    __shared__ unsigned long long red[256];
    __shared__ float su[64];
    int t = threadIdx.x;
    int b = blockIdx.x;
    int total = nb * TOPK;

    for (int i = t; i < total; i += 256) {
        int blk = i / TOPK, j = i - blk * TOPK;
        keys[i] = part[((long long)blk * 64 + b) * TOPK + j];
    }
    __syncthreads();

    float mnv = fkey_inv(mm[0]);
    float mxv = fkey_inv(mm[1]);
    float scale = (mxv - mnv) / 255.0f;
    float zp = -mnv / scale;

    unsigned long long bound = ~0ull;
    float sc[TOPK]; int idx[TOPK];
    for (int p = 0; p < TOPK; p++) {
        unsigned long long best = 0ull;
        for (int i = t; i < total; i += 256) {
            unsigned long long k = keys[i];
            if (k < bound && k > best) best = k;
        }
        red[t] = best;
        __syncthreads();
        for (int s = 128; s > 0; s >>= 1) {
            if (t < s) red[t] = red[t] > red[t + s] ? red[t] : red[t + s];
            __syncthreads();
        }
        unsigned long long win = red[0];
        __syncthreads();
        bound = win;
        sc[p] = fkey_inv((unsigned)(win >> 32));
        idx[p] = (int)(~(unsigned)win);
    }

    float w[TOPK]; float Z = 0.f;
    #pragma unroll
    for (int p = 0; p < TOPK; p++) { w[p] = expf(sc[p] - sc[0]); Z += w[p]; }
    #pragma unroll
    for (int p = 0; p < TOPK; p++) w[p] /= Z;

    if (t < 64) {
        float u = 0.f;
        #pragma unroll
        for (int p = 0; p < TOPK; p++) {
            float m = mem[(long long)idx[p] * 64 + t];
            m = (rintf(m / scale + zp) - zp) * scale;
            u += w[p] * m;
        }
        su[t] = u;
    }
    __syncthreads();
    if (t < 64) {
        float o = 0.f;
        #pragma unroll
        for (int e = 0; e < 64; e++) o += su[e] * Wv[t * 64 + e];
        out[b * 64 + t] = o;
    }
}

extern "C" void kernel_launch(void* const* d_in, const int* in_sizes, int n_in,
                              void* d_out, int out_size, void* d_ws, size_t ws_size,
                              hipStream_t stream) {
    const float* query = (const float*)d_in[0];
    const float* mem   = (const float*)d_in[1];
    const float* aw    = (const float*)d_in[2];
    const float* Wq    = (const float*)d_in[3];
    const float* Wk    = (const float*)d_in[4];
    const float* Wv    = (const float*)d_in[5];
    float* out = (float*)d_out;

    unsigned* mm = (unsigned*)d_ws;
    float* qk = (float*)((char*)d_ws + WS_QK_OFF);
    unsigned long long* part = (unsigned long long*)((char*)d_ws + WS_PART_OFF);

    // adapt partial-candidate block count to the workspace we actually have
    int nb = MAX_NB;
    size_t need = WS_PART_OFF + (size_t)MAX_NB * 64 * TOPK * 8;
    if (ws_size < need) {
        size_t avail = ws_size > WS_PART_OFF ? ws_size - WS_PART_OFF : 0;
        nb = (int)(avail / ((size_t)64 * TOPK * 8));
        if (nb < 1) nb = 1;
        if (nb > MAX_NB) nb = MAX_NB;
    }
    int rowsPerBlock = (NROWS + nb - 1) / nb;

    k_init<<<1, 1, 0, stream>>>(mm);
    k_minmax<<<1024, 256, 0, stream>>>((const float4*)mem, NROWS * D / 4, mm);
    k_qk<<<1, 256, 0, stream>>>(query, Wq, Wk, qk);
    k_scores<<<nb, 256, 0, stream>>>(mem, aw, qk, mm, part, rowsPerBlock);
    k_finalize<<<B, 256, 0, stream>>>(part, nb, mem, Wv, mm, out);
}

// Round 2
// 562.143 us; speedup vs baseline: 1.3465x; 1.3465x over previous
//
#include <hip/hip_runtime.h>
#include <stdint.h>

constexpr int NROWS = 1000000;
constexpr int D = 64;
constexpr int B = 64;
constexpr int TOPK = 5;
constexpr int TBLK = 8;      // per-block per-batch candidates kept
constexpr int TRES = 16;     // globally rescored candidates per batch
constexpr int MM_BLOCKS = 2048;
constexpr int NB2MAX = 512;

typedef __attribute__((ext_vector_type(8))) short short8;
typedef __attribute__((ext_vector_type(4))) float floatx4;

// workspace byte offsets
#define OFF_SCALE 0        // scale, zp (2 f32)
#define OFF_CB    256      // cb[64] f32
#define OFF_QKF   512      // qkf[64*64] f32   (16 KB)
#define OFF_QKB   16896    // qkb[64*64] bf16  (8 KB)
#define OFF_MM    25088    // minmax partials 2048*2 u32 (16 KB)
#define OFF_CAND  41472    // cand[nb2*64*TBLK] u64

__device__ __forceinline__ unsigned fkey(float x) {
    unsigned u = __float_as_uint(x);
    return (u & 0x80000000u) ? ~u : (u | 0x80000000u);
}
__device__ __forceinline__ float fkey_inv(unsigned k) {
    unsigned u = (k & 0x80000000u) ? (k ^ 0x80000000u) : ~k;
    return __uint_as_float(u);
}
__device__ __forceinline__ unsigned short f2bf_rne(float x) {
    unsigned u = __float_as_uint(x);
    u += 0x7fffu + ((u >> 16) & 1u);
    return (unsigned short)(u >> 16);
}
// Qc is an integer in [-128,127]: exact in bf16, low f32 bits are zero -> truncate
__device__ __forceinline__ unsigned short int2bf_exact(float q) {
    return (unsigned short)(__float_as_uint(q) >> 16);
}

template<int K>
__device__ __forceinline__ void insert_key(unsigned long long (&ks)[K],
                                           unsigned long long key) {
    if (key > ks[K - 1]) {
        #pragma unroll
        for (int j = K - 1; j > 0; --j)
            ks[j] = (key > ks[j - 1]) ? ks[j - 1] : ((key > ks[j]) ? key : ks[j]);
        ks[0] = (key > ks[0]) ? key : ks[0];
    }
}

__global__ void k_minmax(const float4* __restrict__ mem4, int n4, unsigned* __restrict__ part) {
    int t = threadIdx.x;
    int gid = blockIdx.x * blockDim.x + t;
    int stride = gridDim.x * blockDim.x;
    float mn = 3.402823466e38f, mx = -3.402823466e38f;
    for (int i = gid; i < n4; i += stride) {
        float4 v = mem4[i];
        mn = fminf(mn, fminf(fminf(v.x, v.y), fminf(v.z, v.w)));
        mx = fmaxf(mx, fmaxf(fmaxf(v.x, v.y), fmaxf(v.z, v.w)));
    }
    __shared__ float smn[256], smx[256];
    smn[t] = mn; smx[t] = mx;
    __syncthreads();
    for (int s = 128; s > 0; s >>= 1) {
        if (t < s) {
            smn[t] = fminf(smn[t], smn[t + s]);
            smx[t] = fmaxf(smx[t], smx[t + s]);
        }
        __syncthreads();
    }
    if (t == 0) {
        part[blockIdx.x * 2 + 0] = fkey(smn[0]);
        part[blockIdx.x * 2 + 1] = fkey(smx[0]);
    }
}

// 16 blocks, 4 batches each: reduce minmax partials, q = query@Wq^T,
// qk = q@Wk * 0.125; emit fp32 qk, bf16 qk*scale, cb[b], scale/zp.
__global__ void k_qk(const float* __restrict__ query, const float* __restrict__ Wq,
                     const float* __restrict__ Wk, const unsigned* __restrict__ part,
                     float* __restrict__ scalezp, float* __restrict__ cb,
                     float* __restrict__ qkf, unsigned short* __restrict__ qkb) {
    __shared__ float q[4][64];
    __shared__ float qkrow[4][64];
    __shared__ unsigned rmn[256], rmx[256];
    int t = threadIdx.x;
    unsigned mnk = 0xFFFFFFFFu, mxk = 0u;
    for (int i = t; i < MM_BLOCKS; i += 256) {
        unsigned a = part[2 * i], b2 = part[2 * i + 1];
        mnk = a < mnk ? a : mnk;
        mxk = b2 > mxk ? b2 : mxk;
    }
    rmn[t] = mnk; rmx[t] = mxk;
    __syncthreads();
    for (int s = 128; s > 0; s >>= 1) {
        if (t < s) {
            rmn[t] = rmn[t + s] < rmn[t] ? rmn[t + s] : rmn[t];
            rmx[t] = rmx[t + s] > rmx[t] ? rmx[t + s] : rmx[t];
        }
        __syncthreads();
    }
    float mnv = fkey_inv(rmn[0]), mxv = fkey_inv(rmx[0]);
    float scale = (mxv - mnv) / 255.0f;
    float zp = -mnv / scale;
    if (blockIdx.x == 0 && t == 0) { scalezp[0] = scale; scalezp[1] = zp; }

    int b0 = blockIdx.x * 4;
    int bq = t >> 6, d = t & 63;
    float s1 = 0.f;
    for (int e = 0; e < 64; e++) s1 += query[(b0 + bq) * 64 + e] * Wq[d * 64 + e];
    q[bq][d] = s1;
    __syncthreads();
    float v = 0.f;
    for (int dd = 0; dd < 64; dd++) v += q[bq][dd] * Wk[dd * 64 + d];
    v *= 0.125f;
    qkf[(b0 + bq) * 64 + d] = v;
    qkb[(b0 + bq) * 64 + d] = f2bf_rne(v * scale);
    qkrow[bq][d] = v;
    __syncthreads();
    if (t < 4) {
        float s = 0.f;
        for (int e = 0; e < 64; e++) s += qkrow[t][e];
        cb[b0 + t] = scale * (128.0f - zp) * s;
    }
}

// MFMA candidate scoring: codes bf16 in LDS, D = codes x qk_bf + (aw + cb),
// per-thread gated top-8, block merge to top-8 per batch.
__launch_bounds__(256)
__global__ void k_score(const float* __restrict__ mem, const float* __restrict__ aw,
                        const float* __restrict__ scalezp, const float* __restrict__ cb,
                        const unsigned short* __restrict__ qkb,
                        unsigned long long* __restrict__ cand, int rowsPerBlock) {
    // codes[64][72] ushort (9216 B) + scores[64][68] f32 (17408 B) overlaid with
    // cmerge[256*TBLK] u64 (16384 B) -> 26624 B
    __shared__ __align__(16) char smem[26624];
    __shared__ float awt[64];
    unsigned short (*codes)[72] = (unsigned short (*)[72])smem;
    float (*scores)[68] = (float (*)[68])(smem + 9216);
    unsigned long long* cmerge = (unsigned long long*)smem;

    int t = threadIdx.x;
    int l15 = t & 15, quad = (t >> 4) & 3, w = t >> 6;
    int b = t & 63;

    float scale = scalezp[0], zp = scalezp[1];
    float inv_scale = 1.0f / scale;

    // B fragments: B[k=quad*8+j][n=l15] from qkb[b][d], b = bt*16+l15, d = kb*32+quad*8+j
    short8 bq[4][2];
    float cbf[4];
    #pragma unroll
    for (int bt = 0; bt < 4; bt++) {
        #pragma unroll
        for (int kb = 0; kb < 2; kb++)
            bq[bt][kb] = *(const short8*)(qkb + (bt * 16 + l15) * 64 + kb * 32 + quad * 8);
        cbf[bt] = cb[bt * 16 + l15];
    }

    unsigned long long ks[TBLK];
    #pragma unroll
    for (int j = 0; j < TBLK; j++) ks[j] = 0ull;

    int row0 = blockIdx.x * rowsPerBlock;
    int rowEnd = min(row0 + rowsPerBlock, NROWS);

    for (int base = row0; base < rowEnd; base += 64) {
        __syncthreads();  // previous tile fully consumed
        // stage: read 64 rows fp32, quantize to Qc bf16 codes
        #pragma unroll
        for (int i = 0; i < 4; i++) {
            int flat = (i * 256 + t) * 4;
            int g = base * 64 + flat;
            float4 v = make_float4(0.f, 0.f, 0.f, 0.f);
            if (g < NROWS * 64) v = *(const float4*)(mem + g);
            ushort4 c;
            c.x = int2bf_exact(rintf(fmaf(v.x, inv_scale, zp)) - 128.0f);
            c.y = int2bf_exact(rintf(fmaf(v.y, inv_scale, zp)) - 128.0f);
            c.z = int2bf_exact(rintf(fmaf(v.z, inv_scale, zp)) - 128.0f);
            c.w = int2bf_exact(rintf(fmaf(v.w, inv_scale, zp)) - 128.0f);
            int r = flat >> 6, dd = flat & 63;
            *(ushort4*)&codes[r][dd] = c;
        }
        if (t < 64) awt[t] = (base + t < NROWS) ? aw[base + t] : 0.f;
        __syncthreads();

        // A fragments: A[m=l15][k=quad*8+j], rows w*16 + l15
        short8 a0 = *(const short8*)&codes[w * 16 + l15][quad * 8];
        short8 a1 = *(const short8*)&codes[w * 16 + l15][32 + quad * 8];
        float aw4[4];
        #pragma unroll
        for (int r = 0; r < 4; r++) aw4[r] = awt[w * 16 + quad * 4 + r];

        #pragma unroll
        for (int bt = 0; bt < 4; bt++) {
            floatx4 acc = {aw4[0] + cbf[bt], aw4[1] + cbf[bt],
                           aw4[2] + cbf[bt], aw4[3] + cbf[bt]};
            acc = __builtin_amdgcn_mfma_f32_16x16x32_bf16(a0, bq[bt][0], acc, 0, 0, 0);
            acc = __builtin_amdgcn_mfma_f32_16x16x32_bf16(a1, bq[bt][1], acc, 0, 0, 0);
            // D: col(batch)=l15, row(m)=quad*4+reg -> scores[batch][row] contiguous b128
            *(floatx4*)&scores[bt * 16 + l15][w * 16 + quad * 4] = acc;
        }

        // scan: thread reads rows [w*16, w*16+16) of its batch — written by its OWN
        // wave (per-wave lgkmcnt ordering), no extra barrier needed.
        #pragma unroll
        for (int j = 0; j < 4; j++) {
            floatx4 v = *(const floatx4*)&scores[b][w * 16 + 4 * j];
            #pragma unroll
            for (int c2 = 0; c2 < 4; c2++) {
                int gr = base + w * 16 + 4 * j + c2;
                if (gr < rowEnd) {
                    unsigned long long key =
                        ((unsigned long long)fkey(v[c2]) << 32) | (unsigned)(~(unsigned)gr);
                    insert_key<TBLK>(ks, key);
                }
            }
        }
    }

    __syncthreads();
    #pragma unroll
    for (int j = 0; j < TBLK; j++) cmerge[t * TBLK + j] = ks[j];
    __syncthreads();
    if (t < 64) {
        unsigned long long ts[TBLK];
        #pragma unroll
        for (int j = 0; j < TBLK; j++) ts[j] = 0ull;
        for (int ww = 0; ww < 4; ww++)
            #pragma unroll
            for (int j = 0; j < TBLK; j++)
                insert_key<TBLK>(ts, cmerge[(ww * 64 + t) * TBLK + j]);
        #pragma unroll
        for (int j = 0; j < TBLK; j++)
            cand[((long long)blockIdx.x * 64 + t) * TBLK + j] = ts[j];
    }
}

// One block per batch: merge nb2*TBLK approx candidates -> top-16, exact fp32
// rescore, top-5, softmax, weighted dequant row sum, @ Wv^T.
__global__ void k_finalize(const unsigned long long* __restrict__ cand, int nb2,
                           const float* __restrict__ mem, const float* __restrict__ aw,
                           const float* __restrict__ Wv, const float* __restrict__ scalezp,
                           const float* __restrict__ qkf, float* __restrict__ out) {
    __shared__ unsigned long long keys[NB2MAX * TBLK];
    __shared__ unsigned long long red[256];
    __shared__ float qkr[64];
    __shared__ int exid[TRES];
    __shared__ unsigned long long exkey[TRES];
    __shared__ float exsc[TRES];
    __shared__ float wsel[TOPK];
    __shared__ int isel[TOPK];
    __shared__ float su[64];

    int t = threadIdx.x, b = blockIdx.x;
    int total = nb2 * TBLK;
    for (int i = t; i < total; i += 256) {
        int blk = i / TBLK, j = i - blk * TBLK;
        keys[i] = cand[((long long)blk * 64 + b) * TBLK + j];
    }
    if (t < 64) qkr[t] = qkf[b * 64 + t];
    __syncthreads();

    float scale = scalezp[0], zp = scalezp[1];

    unsigned long long bound = ~0ull;
    for (int p = 0; p < TRES; p++) {
        unsigned long long best = 0ull;
        for (int i = t; i < total; i += 256) {
            unsigned long long k = keys[i];
            if (k < bound && k > best) best = k;
        }
        red[t] = best;
        __syncthreads();
        for (int s = 128; s > 0; s >>= 1) {
            if (t < s) red[t] = red[t] > red[t + s] ? red[t] : red[t + s];
            __syncthreads();
        }
        unsigned long long win = red[0];
        __syncthreads();
        bound = win;
        if (t == 0) exid[p] = (win == 0ull) ? 0 : (int)(~(unsigned)win);
    }
    __syncthreads();

    // exact rescore (mirrors reference: divide, rint, fp32)
    int lane = t & 63, w = t >> 6;
    for (int i = 0; i < 4; i++) {
        int c = w * 4 + i;
        int idx = exid[c];
        float m = mem[(long long)idx * 64 + lane];
        float dq = (rintf(m / scale + zp) - zp) * scale;
        float p2 = dq * qkr[lane];
        for (int o = 32; o > 0; o >>= 1) p2 += __shfl_xor(p2, o);
        if (lane == 0) {
            float ex = p2 + aw[idx];
            exsc[c] = ex;
            exkey[c] = ((unsigned long long)fkey(ex) << 32) | (unsigned)(~(unsigned)idx);
        }
    }
    __syncthreads();

    if (t == 0) {
        unsigned long long bnd = ~0ull;
        float ssel[TOPK];
        for (int p = 0; p < TOPK; p++) {
            unsigned long long best = 0ull; int bc = 0;
            for (int c = 0; c < TRES; c++) {
                unsigned long long k = exkey[c];
                if (k < bnd && k > best) { best = k; bc = c; }
            }
            bnd = best;
            ssel[p] = exsc[bc];
            isel[p] = exid[bc];
        }
        float Z = 0.f;
        for (int p = 0; p < TOPK; p++) { wsel[p] = expf(ssel[p] - ssel[0]); Z += wsel[p]; }
        for (int p = 0; p < TOPK; p++) wsel[p] /= Z;
    }
    __syncthreads();

    if (t < 64) {
        float u = 0.f;
        #pragma unroll
        for (int p = 0; p < TOPK; p++) {
            float m = mem[(long long)isel[p] * 64 + t];
            float dq = (rintf(m / scale + zp) - zp) * scale;
            u += wsel[p] * dq;
        }
        su[t] = u;
    }
    __syncthreads();
    if (t < 64) {
        float o = 0.f;
        #pragma unroll
        for (int e = 0; e < 64; e++) o += su[e] * Wv[t * 64 + e];
        out[b * 64 + t] = o;
    }
}

extern "C" void kernel_launch(void* const* d_in, const int* in_sizes, int n_in,
                              void* d_out, int out_size, void* d_ws, size_t ws_size,
                              hipStream_t stream) {
    const float* query = (const float*)d_in[0];
    const float* mem   = (const float*)d_in[1];
    const float* aw    = (const float*)d_in[2];
    const float* Wq    = (const float*)d_in[3];
    const float* Wk    = (const float*)d_in[4];
    const float* Wv    = (const float*)d_in[5];
    float* out = (float*)d_out;

    char* ws = (char*)d_ws;
    float* scalezp = (float*)(ws + OFF_SCALE);
    float* cb      = (float*)(ws + OFF_CB);
    float* qkf     = (float*)(ws + OFF_QKF);
    unsigned short* qkb = (unsigned short*)(ws + OFF_QKB);
    unsigned* part = (unsigned*)(ws + OFF_MM);
    unsigned long long* cand = (unsigned long long*)(ws + OFF_CAND);

    int nb2 = NB2MAX;
    size_t need = (size_t)OFF_CAND + (size_t)nb2 * 64 * TBLK * 8;
    if (ws_size < need) {
        size_t avail = ws_size > OFF_CAND ? ws_size - OFF_CAND : 0;
        nb2 = (int)(avail / ((size_t)64 * TBLK * 8));
        if (nb2 < 8) nb2 = 8;
        if (nb2 > NB2MAX) nb2 = NB2MAX;
    }
    int rpb = (NROWS + nb2 - 1) / nb2;

    k_minmax<<<MM_BLOCKS, 256, 0, stream>>>((const float4*)mem, NROWS * D / 4, part);
    k_qk<<<16, 256, 0, stream>>>(query, Wq, Wk, part, scalezp, cb, qkf, qkb);
    k_score<<<nb2, 256, 0, stream>>>(mem, aw, scalezp, cb, qkb, cand, rpb);
    k_finalize<<<B, 256, 0, stream>>>(cand, nb2, mem, aw, Wv, scalezp, qkf, out);
}

// Round 3
// 537.460 us; speedup vs baseline: 1.4083x; 1.0459x over previous
//
#include <hip/hip_runtime.h>
#include <stdint.h>

constexpr int NROWS = 1000000;
constexpr int D = 64;
constexpr int B = 64;
constexpr int TOPK = 5;
constexpr int TBLK = 8;      // per-block per-batch candidates kept
constexpr int TRES = 16;     // globally rescored candidates per batch
constexpr int MM_BLOCKS = 4096;
constexpr int NB2MAX = 1280; // 5 blocks/CU, fully resident

typedef __attribute__((ext_vector_type(8))) short short8;
typedef __attribute__((ext_vector_type(4))) float floatx4;

// workspace byte offsets
#define OFF_SCALE 0        // scale, zp (2 f32)
#define OFF_CB    256      // cb[64] f32
#define OFF_QKF   512      // qkf[64*64] f32   (16 KB)
#define OFF_QKB   16896    // qkb[64*64] bf16  (8 KB)
#define OFF_MM    25088    // minmax partials 4096*2 u32 (32 KB)
#define OFF_CAND  57856    // cand[nb2*64*TBLK] u64

__device__ __forceinline__ unsigned fkey(float x) {
    unsigned u = __float_as_uint(x);
    return (u & 0x80000000u) ? ~u : (u | 0x80000000u);
}
__device__ __forceinline__ float fkey_inv(unsigned k) {
    unsigned u = (k & 0x80000000u) ? (k ^ 0x80000000u) : ~k;
    return __uint_as_float(u);
}
__device__ __forceinline__ unsigned short f2bf_rne(float x) {
    unsigned u = __float_as_uint(x);
    u += 0x7fffu + ((u >> 16) & 1u);
    return (unsigned short)(u >> 16);
}
// Qc is an integer in [-128,127]: exact in bf16, low f32 bits are zero -> truncate
__device__ __forceinline__ unsigned short int2bf_exact(float q) {
    return (unsigned short)(__float_as_uint(q) >> 16);
}

template<int K>
__device__ __forceinline__ void insert_key(unsigned long long (&ks)[K],
                                           unsigned long long key) {
    if (key > ks[K - 1]) {
        #pragma unroll
        for (int j = K - 1; j > 0; --j)
            ks[j] = (key > ks[j - 1]) ? ks[j - 1] : ((key > ks[j]) ? key : ks[j]);
        ks[0] = (key > ks[0]) ? key : ks[0];
    }
}

__global__ void k_minmax(const float4* __restrict__ mem4, int n4, unsigned* __restrict__ part) {
    int t = threadIdx.x;
    int gid = blockIdx.x * blockDim.x + t;
    int stride = gridDim.x * blockDim.x;
    float mn = 3.402823466e38f, mx = -3.402823466e38f;
    for (int i = gid; i < n4; i += stride) {
        float4 v = mem4[i];
        mn = fminf(mn, fminf(fminf(v.x, v.y), fminf(v.z, v.w)));
        mx = fmaxf(mx, fmaxf(fmaxf(v.x, v.y), fmaxf(v.z, v.w)));
    }
    __shared__ float smn[256], smx[256];
    smn[t] = mn; smx[t] = mx;
    __syncthreads();
    for (int s = 128; s > 0; s >>= 1) {
        if (t < s) {
            smn[t] = fminf(smn[t], smn[t + s]);
            smx[t] = fmaxf(smx[t], smx[t + s]);
        }
        __syncthreads();
    }
    if (t == 0) {
        part[blockIdx.x * 2 + 0] = fkey(smn[0]);
        part[blockIdx.x * 2 + 1] = fkey(smx[0]);
    }
}

// 16 blocks, 4 batches each: reduce minmax partials, q = query@Wq^T,
// qk = q@Wk * 0.125; emit fp32 qk, bf16 qk*scale, cb[b], scale/zp.
__global__ void k_qk(const float* __restrict__ query, const float* __restrict__ Wq,
                     const float* __restrict__ Wk, const unsigned* __restrict__ part,
                     float* __restrict__ scalezp, float* __restrict__ cb,
                     float* __restrict__ qkf, unsigned short* __restrict__ qkb) {
    __shared__ float q[4][64];
    __shared__ float qkrow[4][64];
    __shared__ unsigned rmn[256], rmx[256];
    int t = threadIdx.x;
    unsigned mnk = 0xFFFFFFFFu, mxk = 0u;
    for (int i = t; i < MM_BLOCKS; i += 256) {
        unsigned a = part[2 * i], b2 = part[2 * i + 1];
        mnk = a < mnk ? a : mnk;
        mxk = b2 > mxk ? b2 : mxk;
    }
    rmn[t] = mnk; rmx[t] = mxk;
    __syncthreads();
    for (int s = 128; s > 0; s >>= 1) {
        if (t < s) {
            rmn[t] = rmn[t + s] < rmn[t] ? rmn[t + s] : rmn[t];
            rmx[t] = rmx[t + s] > rmx[t] ? rmx[t + s] : rmx[t];
        }
        __syncthreads();
    }
    float mnv = fkey_inv(rmn[0]), mxv = fkey_inv(rmx[0]);
    float scale = (mxv - mnv) / 255.0f;
    float zp = -mnv / scale;
    if (blockIdx.x == 0 && t == 0) { scalezp[0] = scale; scalezp[1] = zp; }

    int b0 = blockIdx.x * 4;
    int bq = t >> 6, d = t & 63;
    float s1 = 0.f;
    for (int e = 0; e < 64; e++) s1 += query[(b0 + bq) * 64 + e] * Wq[d * 64 + e];
    q[bq][d] = s1;
    __syncthreads();
    float v = 0.f;
    for (int dd = 0; dd < 64; dd++) v += q[bq][dd] * Wk[dd * 64 + d];
    v *= 0.125f;
    qkf[(b0 + bq) * 64 + d] = v;
    qkb[(b0 + bq) * 64 + d] = f2bf_rne(v * scale);
    qkrow[bq][d] = v;
    __syncthreads();
    if (t < 4) {
        float s = 0.f;
        for (int e = 0; e < 64; e++) s += qkrow[t][e];
        cb[b0 + t] = scale * (128.0f - zp) * s;
    }
}

// MFMA candidate scoring with register-prefetch pipeline + raw barriers
// (no vmcnt drain at barriers -> prefetch overlaps compute).
__launch_bounds__(256, 5)
__global__ void k_score(const float* __restrict__ mem, const float* __restrict__ aw,
                        const float* __restrict__ scalezp, const float* __restrict__ cb,
                        const unsigned short* __restrict__ qkb,
                        unsigned long long* __restrict__ cand, int rowsPerBlock) {
    // codes[64][72] ushort (9216 B) + scores[64][68] f32 (17408 B) overlaid with
    // cmerge[256*TBLK] u64 (16384 B) -> 26624 B
    __shared__ __align__(16) char smem[26624];
    __shared__ float awt[64];
    unsigned short (*codes)[72] = (unsigned short (*)[72])smem;
    float (*scores)[68] = (float (*)[68])(smem + 9216);
    unsigned long long* cmerge = (unsigned long long*)smem;

    int t = threadIdx.x;
    int l15 = t & 15, quad = (t >> 4) & 3, w = t >> 6;
    int b = t & 63;

    float scale = scalezp[0], zp = scalezp[1];
    float inv_scale = 1.0f / scale;

    // B fragments: B[k=quad*8+j][n=l15] from qkb[b][d]
    short8 bq[4][2];
    float cbf[4];
    #pragma unroll
    for (int bt = 0; bt < 4; bt++) {
        #pragma unroll
        for (int kb = 0; kb < 2; kb++)
            bq[bt][kb] = *(const short8*)(qkb + (bt * 16 + l15) * 64 + kb * 32 + quad * 8);
        cbf[bt] = cb[bt * 16 + l15];
    }

    unsigned long long ks[TBLK];
    #pragma unroll
    for (int j = 0; j < TBLK; j++) ks[j] = 0ull;

    int row0 = blockIdx.x * rowsPerBlock;
    int rowEnd = min(row0 + rowsPerBlock, NROWS);

    // prologue prefetch: tile 0 into registers
    float4 pre[4];
    float preaw = 0.f;
    {
        int base = row0 < NROWS ? row0 : 0;
        #pragma unroll
        for (int i = 0; i < 4; i++) {
            int flat = (i * 256 + t) * 4;
            int g = base * 64 + flat;
            if (g > NROWS * 64 - 4) g = NROWS * 64 - 4;
            pre[i] = *(const float4*)(mem + g);
        }
        if (t < 64) {
            int ai = base + t; if (ai > NROWS - 1) ai = NROWS - 1;
            preaw = aw[ai];
        }
    }

    for (int base = row0; base < rowEnd; base += 64) {
        // quantize prefetched tile (vmcnt wait auto-inserted at first use)
        #pragma unroll
        for (int i = 0; i < 4; i++) {
            float4 v = pre[i];
            ushort4 c;
            c.x = int2bf_exact(rintf(fmaf(v.x, inv_scale, zp)) - 128.0f);
            c.y = int2bf_exact(rintf(fmaf(v.y, inv_scale, zp)) - 128.0f);
            c.z = int2bf_exact(rintf(fmaf(v.z, inv_scale, zp)) - 128.0f);
            c.w = int2bf_exact(rintf(fmaf(v.w, inv_scale, zp)) - 128.0f);
            int flat = (i * 256 + t) * 4;
            *(ushort4*)&codes[flat >> 6][flat & 63] = c;
        }
        if (t < 64) awt[t] = preaw;

        // issue prefetch for next tile (stays in flight across raw barriers)
        int nbase = (base + 64 < rowEnd) ? base + 64 : base;
        #pragma unroll
        for (int i = 0; i < 4; i++) {
            int flat = (i * 256 + t) * 4;
            int g = nbase * 64 + flat;
            if (g > NROWS * 64 - 4) g = NROWS * 64 - 4;
            pre[i] = *(const float4*)(mem + g);
        }
        if (t < 64) {
            int ai = nbase + t; if (ai > NROWS - 1) ai = NROWS - 1;
            preaw = aw[ai];
        }

        asm volatile("s_waitcnt lgkmcnt(0)" ::: "memory");
        __builtin_amdgcn_s_barrier();   // codes tile visible to all waves

        // A fragments: rows w*16 + l15
        short8 a0 = *(const short8*)&codes[w * 16 + l15][quad * 8];
        short8 a1 = *(const short8*)&codes[w * 16 + l15][32 + quad * 8];
        float aw4[4];
        #pragma unroll
        for (int r = 0; r < 4; r++) aw4[r] = awt[w * 16 + quad * 4 + r];

        #pragma unroll
        for (int bt = 0; bt < 4; bt++) {
            floatx4 acc = {aw4[0] + cbf[bt], aw4[1] + cbf[bt],
                           aw4[2] + cbf[bt], aw4[3] + cbf[bt]};
            acc = __builtin_amdgcn_mfma_f32_16x16x32_bf16(a0, bq[bt][0], acc, 0, 0, 0);
            acc = __builtin_amdgcn_mfma_f32_16x16x32_bf16(a1, bq[bt][1], acc, 0, 0, 0);
            *(floatx4*)&scores[bt * 16 + l15][w * 16 + quad * 4] = acc;
        }

        // scan rows [w*16, w*16+16) of this thread's batch (written by own wave)
        #pragma unroll
        for (int j = 0; j < 4; j++) {
            floatx4 v = *(const floatx4*)&scores[b][w * 16 + 4 * j];
            #pragma unroll
            for (int c2 = 0; c2 < 4; c2++) {
                int gr = base + w * 16 + 4 * j + c2;
                if (gr < rowEnd) {
                    unsigned long long key =
                        ((unsigned long long)fkey(v[c2]) << 32) | (unsigned)(~(unsigned)gr);
                    insert_key<TBLK>(ks, key);
                }
            }
        }

        asm volatile("s_waitcnt lgkmcnt(0)" ::: "memory");
        __builtin_amdgcn_s_barrier();   // tile fully consumed
    }

    __syncthreads();
    #pragma unroll
    for (int j = 0; j < TBLK; j++) cmerge[t * TBLK + j] = ks[j];
    __syncthreads();
    if (t < 64) {
        unsigned long long ts[TBLK];
        #pragma unroll
        for (int j = 0; j < TBLK; j++) ts[j] = 0ull;
        for (int ww = 0; ww < 4; ww++)
            #pragma unroll
            for (int j = 0; j < TBLK; j++)
                insert_key<TBLK>(ts, cmerge[(ww * 64 + t) * TBLK + j]);
        #pragma unroll
        for (int j = 0; j < TBLK; j++)
            cand[((long long)blockIdx.x * 64 + t) * TBLK + j] = ts[j];
    }
}

// One block per batch: per-thread gated top-16 over strided candidates,
// 8-level pairwise sorted-merge tree, exact fp32 rescore of top-16, top-5,
// softmax, weighted dequant row sum, @ Wv^T.
__global__ void k_finalize(const unsigned long long* __restrict__ cand, int nb2,
                           const float* __restrict__ mem, const float* __restrict__ aw,
                           const float* __restrict__ Wv, const float* __restrict__ scalezp,
                           const float* __restrict__ qkf, float* __restrict__ out) {
    __shared__ unsigned long long lists[256][TRES];   // 32 KB
    __shared__ float qkr[64];
    __shared__ int exid[TRES];
    __shared__ unsigned long long exkey[TRES];
    __shared__ float exsc[TRES];
    __shared__ float wsel[TOPK];
    __shared__ int isel[TOPK];
    __shared__ float su[64];

    int t = threadIdx.x, b = blockIdx.x;
    int total = nb2 * TBLK;

    unsigned long long loc[TRES];
    #pragma unroll
    for (int j = 0; j < TRES; j++) loc[j] = 0ull;
    for (int i = t; i < total; i += 256) {
        int blk = i / TBLK, j = i - blk * TBLK;
        insert_key<TRES>(loc, cand[((long long)blk * 64 + b) * TBLK + j]);
    }
    #pragma unroll
    for (int j = 0; j < TRES; j++) lists[t][j] = loc[j];
    if (t < 64) qkr[t] = qkf[b * 64 + t];
    __syncthreads();

    for (int s = 128; s > 0; s >>= 1) {
        if (t < s) {
            #pragma unroll
            for (int j = 0; j < TRES; j++) insert_key<TRES>(loc, lists[t + s][j]);
            #pragma unroll
            for (int j = 0; j < TRES; j++) lists[t][j] = loc[j];
        }
        __syncthreads();
    }
    if (t < TRES) {
        unsigned long long k = lists[0][t];
        exid[t] = k ? (int)(~(unsigned)k) : 0;
    }
    __syncthreads();

    float scale = scalezp[0], zp = scalezp[1];

    // exact rescore (mirrors reference: divide, rint, fp32)
    int lane = t & 63, w = t >> 6;
    for (int i = 0; i < 4; i++) {
        int c = w * 4 + i;
        int idx = exid[c];
        float m = mem[(long long)idx * 64 + lane];
        float dq = (rintf(m / scale + zp) - zp) * scale;
        float p2 = dq * qkr[lane];
        for (int o = 32; o > 0; o >>= 1) p2 += __shfl_xor(p2, o);
        if (lane == 0) {
            float ex = p2 + aw[idx];
            exsc[c] = ex;
            exkey[c] = ((unsigned long long)fkey(ex) << 32) | (unsigned)(~(unsigned)idx);
        }
    }
    __syncthreads();

    if (t == 0) {
        unsigned long long bnd = ~0ull;
        float ssel[TOPK];
        for (int p = 0; p < TOPK; p++) {
            unsigned long long best = 0ull; int bc = 0;
            for (int c = 0; c < TRES; c++) {
                unsigned long long k = exkey[c];
                if (k < bnd && k > best) { best = k; bc = c; }
            }
            bnd = best;
            ssel[p] = exsc[bc];
            isel[p] = exid[bc];
        }
        float Z = 0.f;
        for (int p = 0; p < TOPK; p++) { wsel[p] = expf(ssel[p] - ssel[0]); Z += wsel[p]; }
        for (int p = 0; p < TOPK; p++) wsel[p] /= Z;
    }
    __syncthreads();

    if (t < 64) {
        float u = 0.f;
        #pragma unroll
        for (int p = 0; p < TOPK; p++) {
            float m = mem[(long long)isel[p] * 64 + t];
            float dq = (rintf(m / scale + zp) - zp) * scale;
            u += wsel[p] * dq;
        }
        su[t] = u;
    }
    __syncthreads();
    if (t < 64) {
        float o = 0.f;
        #pragma unroll
        for (int e = 0; e < 64; e++) o += su[e] * Wv[t * 64 + e];
        out[b * 64 + t] = o;
    }
}

extern "C" void kernel_launch(void* const* d_in, const int* in_sizes, int n_in,
                              void* d_out, int out_size, void* d_ws, size_t ws_size,
                              hipStream_t stream) {
    const float* query = (const float*)d_in[0];
    const float* mem   = (const float*)d_in[1];
    const float* aw    = (const float*)d_in[2];
    const float* Wq    = (const float*)d_in[3];
    const float* Wk    = (const float*)d_in[4];
    const float* Wv    = (const float*)d_in[5];
    float* out = (float*)d_out;

    char* ws = (char*)d_ws;
    float* scalezp = (float*)(ws + OFF_SCALE);
    float* cb      = (float*)(ws + OFF_CB);
    float* qkf     = (float*)(ws + OFF_QKF);
    unsigned short* qkb = (unsigned short*)(ws + OFF_QKB);
    unsigned* part = (unsigned*)(ws + OFF_MM);
    unsigned long long* cand = (unsigned long long*)(ws + OFF_CAND);

    int nb2 = NB2MAX;
    size_t need = (size_t)OFF_CAND + (size_t)nb2 * 64 * TBLK * 8;
    if (ws_size < need) {
        size_t avail = ws_size > OFF_CAND ? ws_size - OFF_CAND : 0;
        nb2 = (int)(avail / ((size_t)64 * TBLK * 8));
        if (nb2 < 8) nb2 = 8;
        if (nb2 > NB2MAX) nb2 = NB2MAX;
    }
    int rpb = (NROWS + nb2 - 1) / nb2;

    k_minmax<<<MM_BLOCKS, 256, 0, stream>>>((const float4*)mem, NROWS * D / 4, part);
    k_qk<<<16, 256, 0, stream>>>(query, Wq, Wk, part, scalezp, cb, qkf, qkb);
    k_score<<<nb2, 256, 0, stream>>>(mem, aw, scalezp, cb, qkb, cand, rpb);
    k_finalize<<<B, 256, 0, stream>>>(cand, nb2, mem, aw, Wv, scalezp, qkf, out);
}